// Round 1
// baseline (482.142 us; speedup 1.0000x reference)
//
#include <hip/hip_runtime.h>
#include <hip/hip_bf16.h>

// ---------------------------------------------------------------------------
// Problem: concat(x1,x2) -> LSTM(551->128, T=5) -> MLP 640->531->256->64->2 -> softmax
// B=16384, T=5, F1=300, F2=251, IN=551, H=128, 4H=512
// Strategy: bf16 MFMA (16x16x32) everywhere, fp32 accumulate.
//   prep      : repack weights fp32->bf16 with zero-padded tiles
//   k1_xgemm  : xg[81920][512] = concat(x)@W_ih^T + (b_ih+b_hh)   (bf16 out)
//   k2_rec    : fused 5-step recurrence, W_hh in registers, h via LDS
//   mlp       : fused 4-layer MLP + softmax
// ---------------------------------------------------------------------------

typedef short  short8 __attribute__((ext_vector_type(8)));   // 8 x bf16 (raw bits)
typedef float  f32x4  __attribute__((ext_vector_type(4)));

#define MFMA(a, b, c) __builtin_amdgcn_mfma_f32_16x16x32_bf16((a), (b), (c), 0, 0, 0)

__device__ __forceinline__ short f2bs(float f) {
    __hip_bfloat16 h = __float2bfloat16(f);   // RNE
    union { __hip_bfloat16 h; short s; } u; u.h = h; return u.s;
}
__device__ __forceinline__ float b2f(short s) {
    union { unsigned u; float f; } v; v.u = ((unsigned)(unsigned short)s) << 16; return v.f;
}
__device__ __forceinline__ float sigf(float x)  { return 1.f / (1.f + __expf(-x)); }
__device__ __forceinline__ float mytanh(float x){ return 2.f / (1.f + __expf(-2.f * x)) - 1.f; }

// ---------------- constants ----------------
#define BB     16384
#define TT     5
#define F1     300
#define F2     251
#define INF    551          // input features
#define KP     576          // padded K for input GEMM
#define G4     512          // 4*H
#define HH     128
#define FLAT   640          // T*H
#define L1N    531
#define L1P    576          // padded (36 tiles, 9 per wave)
#define L1KP   544          // K-pad of 531 for layer2
#define L2N    256
#define L3N    64

// ws offsets (bytes) — all 256-aligned
#define O_WIH  0u
#define O_WHH  589824u
#define O_W1   720896u
#define O_W2   1458176u
#define O_W3   1736704u
#define O_BG   1769472u
#define O_B1   1771520u
#define O_XG   1773824u
#define O_HS   85659904u
#define WS_NEED 106631424u

// ---------------------------------------------------------------------------
// prep: weight repack fp32 -> bf16 (zero-padded)
// ---------------------------------------------------------------------------
__global__ void prep_kernel(
    const float* __restrict__ W_ih, const float* __restrict__ W_hh,
    const float* __restrict__ b_ih, const float* __restrict__ b_hh,
    const float* __restrict__ W1,   const float* __restrict__ b1,
    const float* __restrict__ W2,   const float* __restrict__ W3,
    short* __restrict__ Wihp, short* __restrict__ Whhp, float* __restrict__ biasg,
    short* __restrict__ W1p,  float* __restrict__ b1p,  short* __restrict__ W2p,
    short* __restrict__ W3p)
{
    const int N0 = G4 * KP;            // Wihp  294912
    const int N1 = N0 + G4 * HH;       // Whhp
    const int N2 = N1 + L1P * FLAT;    // W1p
    const int N3 = N2 + L2N * L1KP;    // W2p
    const int N4 = N3 + L3N * L2N;     // W3p
    const int N5 = N4 + G4;            // biasg
    const int N6 = N5 + L1P;           // b1p
    const int stride = gridDim.x * blockDim.x;
    for (int i = blockIdx.x * blockDim.x + threadIdx.x; i < N6; i += stride) {
        if (i < N0) {
            int n = i / KP, k = i - n * KP;
            Wihp[i] = f2bs(k < INF ? W_ih[n * INF + k] : 0.f);
        } else if (i < N1) {
            int j = i - N0;
            Whhp[j] = f2bs(W_hh[j]);
        } else if (i < N2) {
            int j = i - N1; int n = j / FLAT, k = j - n * FLAT;
            W1p[j] = f2bs(n < L1N ? W1[n * FLAT + k] : 0.f);
        } else if (i < N3) {
            int j = i - N2; int n = j / L1KP, k = j - n * L1KP;
            W2p[j] = f2bs(k < L1N ? W2[n * L1N + k] : 0.f);
        } else if (i < N4) {
            int j = i - N3;
            W3p[j] = f2bs(W3[j]);
        } else if (i < N5) {
            int j = i - N4;
            biasg[j] = b_ih[j] + b_hh[j];
        } else {
            int j = i - N5;
            b1p[j] = (j < L1N) ? b1[j] : 0.f;
        }
    }
}

// ---------------------------------------------------------------------------
// k1_xgemm: xg = concat(x1,x2) @ W_ih^T + bias     M=81920, N=512, K=576(551)
// block: 512 thr (8 waves), BM=64, each wave owns 64 n-cols. A staged in LDS
// (fp32 load + cvt), B-frags streamed from global (L2-resident, 0.59 MB).
// ---------------------------------------------------------------------------
__device__ __forceinline__ float4 load_chunk4(const float* __restrict__ x1,
                                              const float* __restrict__ x2,
                                              int m, int c)
{
    // c is 4-aligned; boundary 300 is 4-aligned, so a chunk never straddles it
    if (c < F1) {
        return *(const float4*)(x1 + m * F1 + c);
    }
    float4 r;
    int base = m * F2 + (c - F1);
    r.x = (c + 0 < INF) ? x2[base + 0] : 0.f;
    r.y = (c + 1 < INF) ? x2[base + 1] : 0.f;
    r.z = (c + 2 < INF) ? x2[base + 2] : 0.f;
    r.w = (c + 3 < INF) ? x2[base + 3] : 0.f;
    return r;
}

__global__ __launch_bounds__(512, 2) void k1_xgemm(
    const float* __restrict__ x1, const float* __restrict__ x2,
    const short* __restrict__ Wihp, const float* __restrict__ biasg,
    short* __restrict__ xg)
{
    __shared__ __align__(16) short At[64][72];   // 64 rows x 64 k (+8 pad)
    const int tid  = threadIdx.x;
    const int w    = tid >> 6;
    const int lane = tid & 63;
    const int quad = lane >> 4;
    const int c16  = lane & 15;
    const int m0   = blockIdx.x * 64;

    f32x4 acc[4][4];
#pragma unroll
    for (int mt = 0; mt < 4; ++mt)
#pragma unroll
        for (int nt = 0; nt < 4; ++nt)
            acc[mt][nt] = (f32x4){0.f, 0.f, 0.f, 0.f};

    const int srow = tid >> 3;          // 0..63
    const int sk0  = (tid & 7) * 8;     // 0..56

    for (int kb = 0; kb < 9; ++kb) {
        __syncthreads();
        {
            int m  = m0 + srow;
            int kg = kb * 64 + sk0;
            float4 c0 = load_chunk4(x1, x2, m, kg);
            float4 c1 = load_chunk4(x1, x2, m, kg + 4);
            short8 s;
            s[0] = f2bs(c0.x); s[1] = f2bs(c0.y); s[2] = f2bs(c0.z); s[3] = f2bs(c0.w);
            s[4] = f2bs(c1.x); s[5] = f2bs(c1.y); s[6] = f2bs(c1.z); s[7] = f2bs(c1.w);
            *(short8*)&At[srow][sk0] = s;
        }
        __syncthreads();
#pragma unroll
        for (int ks = 0; ks < 2; ++ks) {
            short8 a[4];
#pragma unroll
            for (int mt = 0; mt < 4; ++mt)
                a[mt] = *(const short8*)&At[mt * 16 + c16][ks * 32 + quad * 8];
#pragma unroll
            for (int nt = 0; nt < 4; ++nt) {
                int n = w * 64 + nt * 16 + c16;
                short8 b = *(const short8*)&Wihp[n * KP + kb * 64 + ks * 32 + quad * 8];
#pragma unroll
                for (int mt = 0; mt < 4; ++mt)
                    acc[mt][nt] = MFMA(a[mt], b, acc[mt][nt]);
            }
        }
    }
    // epilogue: + bias, store bf16.  C-layout: col=lane&15, row=quad*4+r
#pragma unroll
    for (int nt = 0; nt < 4; ++nt) {
        int n = w * 64 + nt * 16 + c16;
        float bv = biasg[n];
#pragma unroll
        for (int mt = 0; mt < 4; ++mt)
#pragma unroll
            for (int r = 0; r < 4; ++r) {
                int m = m0 + mt * 16 + quad * 4 + r;
                xg[m * G4 + n] = f2bs(acc[mt][nt][r] + bv);
            }
    }
}

// ---------------------------------------------------------------------------
// k2_rec: fused LSTM recurrence. block 512 thr (8 waves), 64 samples/block.
// Wave w owns gate-columns j in [16w,16w+16): gate tiles {g*8+w}, so i/f/g/o
// for one (m,j) land in the same lane -> c stays in registers.
// W_hh B-frags (4 gates x 4 ksteps) preloaded into registers, reused for all t.
// h round-trips through double-buffered LDS (C-layout write -> A-layout read).
// ---------------------------------------------------------------------------
__global__ __launch_bounds__(512, 2) void k2_rec(
    const short* __restrict__ Whhp, const short* __restrict__ xg,
    short* __restrict__ hs)
{
    __shared__ __align__(16) short hb[2][64][136];
    const int tid  = threadIdx.x;
    const int w    = tid >> 6;
    const int lane = tid & 63;
    const int quad = lane >> 4;
    const int c16  = lane & 15;
    const int b0   = blockIdx.x * 64;
    const int j    = w * 16 + c16;          // gate column 0..127

    short8 bfr[4][4];
#pragma unroll
    for (int g = 0; g < 4; ++g)
#pragma unroll
        for (int ks = 0; ks < 4; ++ks)
            bfr[g][ks] = *(const short8*)&Whhp[(g * HH + j) * HH + ks * 32 + quad * 8];

    float cst[4][4];
#pragma unroll
    for (int mt = 0; mt < 4; ++mt)
#pragma unroll
        for (int r = 0; r < 4; ++r) cst[mt][r] = 0.f;

    for (int t = 0; t < TT; ++t) {
        f32x4 acc[4][4];
#pragma unroll
        for (int mt = 0; mt < 4; ++mt)
#pragma unroll
            for (int g = 0; g < 4; ++g)
                acc[mt][g] = (f32x4){0.f, 0.f, 0.f, 0.f};

        if (t > 0) {
            const short (*cur)[136] = hb[(t - 1) & 1];
#pragma unroll
            for (int ks = 0; ks < 4; ++ks) {
                short8 a[4];
#pragma unroll
                for (int mt = 0; mt < 4; ++mt)
                    a[mt] = *(const short8*)&cur[mt * 16 + c16][ks * 32 + quad * 8];
#pragma unroll
                for (int mt = 0; mt < 4; ++mt)
#pragma unroll
                    for (int g = 0; g < 4; ++g)
                        acc[mt][g] = MFMA(a[mt], bfr[g][ks], acc[mt][g]);
            }
        }

        short (*nxt)[136] = hb[t & 1];
#pragma unroll
        for (int mt = 0; mt < 4; ++mt) {
#pragma unroll
            for (int r = 0; r < 4; ++r) {
                int m    = mt * 16 + quad * 4 + r;
                int base = ((b0 + m) * TT + t) * G4 + j;
                float gi = acc[mt][0][r] + b2f(xg[base]);
                float gf = acc[mt][1][r] + b2f(xg[base + 128]);
                float gg = acc[mt][2][r] + b2f(xg[base + 256]);
                float go = acc[mt][3][r] + b2f(xg[base + 384]);
                float cn = sigf(gf) * cst[mt][r] + sigf(gi) * mytanh(gg);
                cst[mt][r] = cn;
                float hv = sigf(go) * mytanh(cn);
                short hv16 = f2bs(hv);
                nxt[m][j] = hv16;
                hs[(b0 + m) * FLAT + t * HH + j] = hv16;
            }
        }
        __syncthreads();
    }
}

// ---------------------------------------------------------------------------
// mlp: fused 640->576(531)->256->64->2 + softmax. block 256 thr (4 waves),
// 32 samples/block. Layer-1 A-frags read straight from global hs (L1/L2 hit);
// later layers' activations live in LDS (59 KB). Weights stream from L2.
// ---------------------------------------------------------------------------
__global__ __launch_bounds__(256, 2) void mlp_kernel(
    const short* __restrict__ hs,
    const short* __restrict__ W1p, const float* __restrict__ b1p,
    const short* __restrict__ W2p, const float* __restrict__ b2,
    const short* __restrict__ W3p, const float* __restrict__ b3,
    const float* __restrict__ W4,  const float* __restrict__ b4,
    float* __restrict__ out)
{
    __shared__ __align__(16) short a1[32][584];   // 576 (+8 pad)
    __shared__ __align__(16) short a2[32][264];   // 256 (+8 pad)
    __shared__ __align__(16) short a3[32][72];    // 64  (+8 pad)
    const int tid  = threadIdx.x;
    const int w    = tid >> 6;
    const int lane = tid & 63;
    const int quad = lane >> 4;
    const int c16  = lane & 15;
    const int m0   = blockIdx.x * 32;

    // ---- layer 1: [32 x 640] @ W1^T -> 576 cols (36 tiles, 9 per wave) ----
    {
        f32x4 acc[2][9];
#pragma unroll
        for (int mt = 0; mt < 2; ++mt)
#pragma unroll
            for (int i = 0; i < 9; ++i)
                acc[mt][i] = (f32x4){0.f, 0.f, 0.f, 0.f};
#pragma unroll 4
        for (int ks = 0; ks < 20; ++ks) {
            short8 a[2];
#pragma unroll
            for (int mt = 0; mt < 2; ++mt)
                a[mt] = *(const short8*)&hs[(m0 + mt * 16 + c16) * FLAT + ks * 32 + quad * 8];
#pragma unroll
            for (int i = 0; i < 9; ++i) {
                int n = (w * 9 + i) * 16 + c16;
                short8 b = *(const short8*)&W1p[n * FLAT + ks * 32 + quad * 8];
                acc[0][i] = MFMA(a[0], b, acc[0][i]);
                acc[1][i] = MFMA(a[1], b, acc[1][i]);
            }
        }
#pragma unroll
        for (int i = 0; i < 9; ++i) {
            int n = (w * 9 + i) * 16 + c16;
            float bv = b1p[n];
#pragma unroll
            for (int mt = 0; mt < 2; ++mt)
#pragma unroll
                for (int r = 0; r < 4; ++r) {
                    int m = mt * 16 + quad * 4 + r;
                    float v = acc[mt][i][r] + bv;
                    a1[m][n] = f2bs(v > 0.f ? v : 0.f);
                }
        }
    }
    __syncthreads();

    // ---- layer 2: K=544, N=256 (4 tiles per wave) ----
    {
        f32x4 acc[2][4];
#pragma unroll
        for (int mt = 0; mt < 2; ++mt)
#pragma unroll
            for (int i = 0; i < 4; ++i)
                acc[mt][i] = (f32x4){0.f, 0.f, 0.f, 0.f};
#pragma unroll 4
        for (int ks = 0; ks < 17; ++ks) {
            short8 a[2];
#pragma unroll
            for (int mt = 0; mt < 2; ++mt)
                a[mt] = *(const short8*)&a1[mt * 16 + c16][ks * 32 + quad * 8];
#pragma unroll
            for (int i = 0; i < 4; ++i) {
                int n = (w * 4 + i) * 16 + c16;
                short8 b = *(const short8*)&W2p[n * L1KP + ks * 32 + quad * 8];
                acc[0][i] = MFMA(a[0], b, acc[0][i]);
                acc[1][i] = MFMA(a[1], b, acc[1][i]);
            }
        }
#pragma unroll
        for (int i = 0; i < 4; ++i) {
            int n = (w * 4 + i) * 16 + c16;
            float bv = b2[n];
#pragma unroll
            for (int mt = 0; mt < 2; ++mt)
#pragma unroll
                for (int r = 0; r < 4; ++r) {
                    int m = mt * 16 + quad * 4 + r;
                    float v = acc[mt][i][r] + bv;
                    a2[m][n] = f2bs(v > 0.f ? v : 0.f);
                }
        }
    }
    __syncthreads();

    // ---- layer 3: K=256, N=64 (1 tile per wave) ----
    {
        f32x4 acc[2];
        acc[0] = (f32x4){0.f, 0.f, 0.f, 0.f};
        acc[1] = (f32x4){0.f, 0.f, 0.f, 0.f};
#pragma unroll
        for (int ks = 0; ks < 8; ++ks) {
            short8 a[2];
#pragma unroll
            for (int mt = 0; mt < 2; ++mt)
                a[mt] = *(const short8*)&a2[mt * 16 + c16][ks * 32 + quad * 8];
            int n = w * 16 + c16;
            short8 b = *(const short8*)&W3p[n * L2N + ks * 32 + quad * 8];
            acc[0] = MFMA(a[0], b, acc[0]);
            acc[1] = MFMA(a[1], b, acc[1]);
        }
        int n = w * 16 + c16;
        float bv = b3[n];
#pragma unroll
        for (int mt = 0; mt < 2; ++mt)
#pragma unroll
            for (int r = 0; r < 4; ++r) {
                int m = mt * 16 + quad * 4 + r;
                float v = acc[mt][r] + bv;
                a3[m][n] = f2bs(v > 0.f ? v : 0.f);
            }
    }
    __syncthreads();

    // ---- layer 4 + softmax: wave 0 only (64 threads = 32 samples x 2 cls) ----
    if (tid < 64) {
        int m   = tid >> 1;
        int cls = tid & 1;
        float s = b4[cls];
#pragma unroll 8
        for (int k = 0; k < 64; ++k)
            s += b2f(a3[m][k]) * W4[cls * 64 + k];
        float other = __shfl_xor(s, 1);
        float p = 1.f / (1.f + __expf(other - s));
        out[(m0 + m) * 2 + cls] = p;
    }
}

// ---------------------------------------------------------------------------
extern "C" void kernel_launch(void* const* d_in, const int* in_sizes, int n_in,
                              void* d_out, int out_size, void* d_ws, size_t ws_size,
                              hipStream_t stream)
{
    (void)in_sizes; (void)n_in; (void)out_size;
    if (ws_size < (size_t)WS_NEED) return;   // fail loudly (validation will catch)

    const float* x1   = (const float*)d_in[0];
    const float* x2   = (const float*)d_in[1];
    const float* W_ih = (const float*)d_in[2];
    const float* W_hh = (const float*)d_in[3];
    const float* b_ih = (const float*)d_in[4];
    const float* b_hh = (const float*)d_in[5];
    const float* W1   = (const float*)d_in[6];
    const float* b1   = (const float*)d_in[7];
    const float* W2   = (const float*)d_in[8];
    const float* b2   = (const float*)d_in[9];
    const float* W3   = (const float*)d_in[10];
    const float* b3   = (const float*)d_in[11];
    const float* W4   = (const float*)d_in[12];
    const float* b4   = (const float*)d_in[13];

    char* ws = (char*)d_ws;
    short* Wihp  = (short*)(ws + O_WIH);
    short* Whhp  = (short*)(ws + O_WHH);
    short* W1p   = (short*)(ws + O_W1);
    short* W2p   = (short*)(ws + O_W2);
    short* W3p   = (short*)(ws + O_W3);
    float* biasg = (float*)(ws + O_BG);
    float* b1p   = (float*)(ws + O_B1);
    short* xg    = (short*)(ws + O_XG);
    short* hsb   = (short*)(ws + O_HS);

    prep_kernel<<<3461, 256, 0, stream>>>(W_ih, W_hh, b_ih, b_hh, W1, b1, W2, W3,
                                          Wihp, Whhp, biasg, W1p, b1p, W2p, W3p);
    k1_xgemm<<<1280, 512, 0, stream>>>(x1, x2, Wihp, biasg, xg);
    k2_rec<<<256, 512, 0, stream>>>(Whhp, xg, hsb);
    mlp_kernel<<<512, 256, 0, stream>>>(hsb, W1p, b1p, W2p, b2, W3p, b3, W4, b4,
                                        (float*)d_out);
}

// Round 2
// 354.933 us; speedup vs baseline: 1.3584x; 1.3584x over previous
//
#include <hip/hip_runtime.h>
#include <hip/hip_bf16.h>

// ---------------------------------------------------------------------------
// concat(x1,x2) -> LSTM(551->128, T=5) -> MLP 640->531->256->64->2 -> softmax
// B=16384, T=5, IN=551, H=128. bf16 MFMA 16x16x32, fp32 accum.
// R2: k1 restructured (half-K LDS staging, 4 barriers total, 2 blocks/CU);
//     ALL intermediate tensors + weights in MFMA-tile-packed layouts so every
//     global access is lane-contiguous; xg reordered [t][b]; k2 512 blocks.
// Packed B/A-tile layout: 16(n|m) x 32(k) tile = 512 elems, element
//   (n,k) -> tile(tn=n>>4, tk=k>>5) at offset lane*8+j, lane=((k>>3)&3)*16+(n&15), j=k&7.
// Packed C-tile layout: 16x16 tile = 256 elems, (m,n) -> offset lane*4+r,
//   lane=((m>>2)&3)*16+(n&15), r=m&3.   (matches MFMA C layout per lane)
// ---------------------------------------------------------------------------

typedef short  short8  __attribute__((ext_vector_type(8)));
typedef short  short4v __attribute__((ext_vector_type(4)));
typedef float  f32x4   __attribute__((ext_vector_type(4)));

#define MFMA(a, b, c) __builtin_amdgcn_mfma_f32_16x16x32_bf16((a), (b), (c), 0, 0, 0)

__device__ __forceinline__ short f2bs(float f) {
    __hip_bfloat16 h = __float2bfloat16(f);   // RNE
    union { __hip_bfloat16 h; short s; } u; u.h = h; return u.s;
}
__device__ __forceinline__ float b2f(short s) {
    union { unsigned u; float f; } v; v.u = ((unsigned)(unsigned short)s) << 16; return v.f;
}
__device__ __forceinline__ float sigf(float x)  { return 1.f / (1.f + __expf(-x)); }
__device__ __forceinline__ float mytanh(float x){ return 2.f / (1.f + __expf(-2.f * x)) - 1.f; }

// ---------------- constants ----------------
#define BB     16384
#define TT     5
#define F1     300
#define F2     251
#define INF    551
#define KP     576          // padded K for input GEMM (18 k-tiles)
#define G4     512
#define HH     128
#define FLAT   640          // T*H (20 k-tiles)
#define L1N    531
#define L1P    576
#define L1KP   544          // 17 k-tiles
#define L2N    256
#define L3N    64

// ws offsets (bytes)
#define O_WIH  0u
#define O_WHH  589824u
#define O_W1   720896u
#define O_W2   1458176u
#define O_W3   1736704u
#define O_BG   1769472u
#define O_B1   1771520u
#define O_XG   1773824u
#define O_HS   85659904u
#define WS_NEED 106631424u

// ---------------------------------------------------------------------------
// prep: weights fp32 -> bf16, packed in B-fragment tile order
// ---------------------------------------------------------------------------
__device__ __forceinline__ void pack_b(const float* __restrict__ W, short* __restrict__ dst,
                                       int i, int tpn, int Nsrc, int Ksrc, int ldw)
{
    int tile = i >> 9, rem = i & 511, lane = rem >> 3, jj = rem & 7;
    int tn = tile / tpn, tk = tile - tn * tpn;
    int n = tn * 16 + (lane & 15);
    int k = tk * 32 + (lane >> 4) * 8 + jj;
    float v = (n < Nsrc && k < Ksrc) ? W[n * ldw + k] : 0.f;
    dst[i] = f2bs(v);
}

__global__ void prep_kernel(
    const float* __restrict__ W_ih, const float* __restrict__ W_hh,
    const float* __restrict__ b_ih, const float* __restrict__ b_hh,
    const float* __restrict__ W1,   const float* __restrict__ b1,
    const float* __restrict__ W2,   const float* __restrict__ W3,
    short* __restrict__ Wihp, short* __restrict__ Whhp, float* __restrict__ biasg,
    short* __restrict__ W1p,  float* __restrict__ b1p,  short* __restrict__ W2p,
    short* __restrict__ W3p)
{
    const int N0 = G4 * KP;            // 294912
    const int N1 = N0 + G4 * HH;       // +65536
    const int N2 = N1 + L1P * FLAT;    // +368640
    const int N3 = N2 + L2N * L1KP;    // +139264
    const int N4 = N3 + L3N * L2N;     // +16384
    const int N5 = N4 + G4;
    const int N6 = N5 + L1P;
    const int stride = gridDim.x * blockDim.x;
    for (int i = blockIdx.x * blockDim.x + threadIdx.x; i < N6; i += stride) {
        if (i < N0)      pack_b(W_ih, Wihp, i,       18, G4,  INF, INF);
        else if (i < N1) pack_b(W_hh, Whhp, i - N0,   4, G4,  HH,  HH);
        else if (i < N2) pack_b(W1,   W1p,  i - N1,  20, L1N, FLAT, FLAT);
        else if (i < N3) pack_b(W2,   W2p,  i - N2,  17, L2N, L1N, L1N);
        else if (i < N4) pack_b(W3,   W3p,  i - N3,   8, L3N, L2N, L2N);
        else if (i < N5) { int j = i - N4; biasg[j] = b_ih[j] + b_hh[j]; }
        else             { int j = i - N5; b1p[j] = (j < L1N) ? b1[j] : 0.f; }
    }
}

// ---------------------------------------------------------------------------
// k1_xgemm: xg = concat(x)@W_ih^T + bias.  M' = t*B + b ordering (81920 rows),
// BM=64, 512 thr. Half-K (288) staged in LDS per barrier-pair -> 144 MFMA/wave
// between barriers. Output in packed C-tiles.
// ---------------------------------------------------------------------------
__device__ __forceinline__ float4 load_chunk4(const float* __restrict__ x1,
                                              const float* __restrict__ x2,
                                              int brow, int t, int c)
{
    if (c < F1) {   // 300 is 4-aligned: no straddle
        return *(const float4*)(x1 + (brow * TT + t) * F1 + c);
    }
    float4 r;
    int base = (brow * TT + t) * F2 + (c - F1);
    r.x = (c + 0 < INF) ? x2[base + 0] : 0.f;
    r.y = (c + 1 < INF) ? x2[base + 1] : 0.f;
    r.z = (c + 2 < INF) ? x2[base + 2] : 0.f;
    r.w = (c + 3 < INF) ? x2[base + 3] : 0.f;
    return r;
}

__global__ __launch_bounds__(512, 4) void k1_xgemm(
    const float* __restrict__ x1, const float* __restrict__ x2,
    const short* __restrict__ Wihp, const float* __restrict__ biasg,
    short* __restrict__ xg)
{
    __shared__ __align__(16) short At[64][296];   // 64 rows x 288 k (+8 pad) = 37.9 KB
    const int tid  = threadIdx.x;
    const int w    = tid >> 6;
    const int lane = tid & 63;
    const int quad = lane >> 4;
    const int c16  = lane & 15;
    const int m0   = blockIdx.x * 64;       // m' = t*B + b
    const int t    = m0 >> 14;              // 64 | 16384 -> whole block same t
    const int bb   = m0 & 16383;

    f32x4 acc[4][4];
#pragma unroll
    for (int mt = 0; mt < 4; ++mt)
#pragma unroll
        for (int nt = 0; nt < 4; ++nt)
            acc[mt][nt] = (f32x4){0.f, 0.f, 0.f, 0.f};

    const int srow  = tid >> 3;            // 0..63
    const int kslot = tid & 7;

    for (int half = 0; half < 2; ++half) {
        __syncthreads();
        {
            int brow = bb + srow;
#pragma unroll
            for (int c = 0; c < 9; ++c) {
                int kl = c * 32 + kslot * 4;
                float4 v = load_chunk4(x1, x2, brow, t, half * 288 + kl);
                short4v s;
                s[0] = f2bs(v.x); s[1] = f2bs(v.y); s[2] = f2bs(v.z); s[3] = f2bs(v.w);
                *(short4v*)&At[srow][kl] = s;
            }
        }
        __syncthreads();
#pragma unroll
        for (int ks = 0; ks < 9; ++ks) {
            short8 a[4];
#pragma unroll
            for (int mt = 0; mt < 4; ++mt)
                a[mt] = *(const short8*)&At[mt * 16 + c16][ks * 32 + quad * 8];
#pragma unroll
            for (int nt = 0; nt < 4; ++nt) {
                int tk = half * 9 + ks;
                short8 b = *(const short8*)&Wihp[(((w * 4 + nt) * 18 + tk) << 9) + lane * 8];
#pragma unroll
                for (int mt = 0; mt < 4; ++mt)
                    acc[mt][nt] = MFMA(a[mt], b, acc[mt][nt]);
            }
        }
    }
    // epilogue: +bias, packed C-tile store (8B/lane, fully coalesced)
#pragma unroll
    for (int nt = 0; nt < 4; ++nt) {
        float bv = biasg[w * 64 + nt * 16 + c16];
#pragma unroll
        for (int mt = 0; mt < 4; ++mt) {
            short4v o;
#pragma unroll
            for (int r = 0; r < 4; ++r) o[r] = f2bs(acc[mt][nt][r] + bv);
            int tm = (m0 >> 4) + mt, tn = w * 4 + nt;
            *(short4v*)&xg[((tm * 32 + tn) << 8) + lane * 4] = o;
        }
    }
}

// ---------------------------------------------------------------------------
// k2_rec: fused LSTM recurrence, 32 samples/block, 512 blocks, 512 thr.
// W_hh B-frags in registers (reused all t). xg read as packed C-tiles (8B/lane).
// h round-trips through LDS; hs exported in packed A-tile layout (16B/lane).
// ---------------------------------------------------------------------------
__global__ __launch_bounds__(512, 2) void k2_rec(
    const short* __restrict__ Whhp, const short* __restrict__ xg,
    short* __restrict__ hs)
{
    __shared__ __align__(16) short hb[2][32][136];
    const int tid  = threadIdx.x;
    const int w    = tid >> 6;
    const int lane = tid & 63;
    const int quad = lane >> 4;
    const int c16  = lane & 15;
    const int btile = blockIdx.x * 2;       // sample-tile base (32 samples)

    short8 bfr[4][4];                       // [gate][ks]
#pragma unroll
    for (int g = 0; g < 4; ++g)
#pragma unroll
        for (int ks = 0; ks < 4; ++ks)
            bfr[g][ks] = *(const short8*)&Whhp[((((g * 8 + w) * 4) + ks) << 9) + lane * 8];

    float cst[2][4];
#pragma unroll
    for (int mt = 0; mt < 2; ++mt)
#pragma unroll
        for (int r = 0; r < 4; ++r) cst[mt][r] = 0.f;

    const int j = w * 16 + c16;

    for (int t = 0; t < TT; ++t) {
        // prefetch gate pre-activations (packed C-tiles)
        short4v xq[2][4];
#pragma unroll
        for (int mt = 0; mt < 2; ++mt)
#pragma unroll
            for (int g = 0; g < 4; ++g)
                xq[mt][g] = *(const short4v*)
                    &xg[((((t << 10) + btile + mt) * 32 + (g * 8 + w)) << 8) + lane * 4];

        f32x4 acc[2][4];
#pragma unroll
        for (int mt = 0; mt < 2; ++mt)
#pragma unroll
            for (int g = 0; g < 4; ++g)
                acc[mt][g] = (f32x4){0.f, 0.f, 0.f, 0.f};

        if (t > 0) {
            const short (*cur)[136] = hb[(t - 1) & 1];
#pragma unroll
            for (int ks = 0; ks < 4; ++ks) {
                short8 a[2];
#pragma unroll
                for (int mt = 0; mt < 2; ++mt)
                    a[mt] = *(const short8*)&cur[mt * 16 + c16][ks * 32 + quad * 8];
#pragma unroll
                for (int mt = 0; mt < 2; ++mt)
#pragma unroll
                    for (int g = 0; g < 4; ++g)
                        acc[mt][g] = MFMA(a[mt], bfr[g][ks], acc[mt][g]);
            }
        }

        short (*nxt)[136] = hb[t & 1];
#pragma unroll
        for (int mt = 0; mt < 2; ++mt) {
#pragma unroll
            for (int r = 0; r < 4; ++r) {
                int m = mt * 16 + quad * 4 + r;
                float gi = acc[mt][0][r] + b2f(xq[mt][0][r]);
                float gf = acc[mt][1][r] + b2f(xq[mt][1][r]);
                float gg = acc[mt][2][r] + b2f(xq[mt][2][r]);
                float go = acc[mt][3][r] + b2f(xq[mt][3][r]);
                float cn = sigf(gf) * cst[mt][r] + sigf(gi) * mytanh(gg);
                cst[mt][r] = cn;
                nxt[m][j] = f2bs(sigf(go) * mytanh(cn));
            }
        }
        __syncthreads();
        // export h_t in packed A-tile layout: wave w -> tile (tm=w>>2, kt=w&3)
        {
            int tm = w >> 2, kt = w & 3;
            short8 v = *(const short8*)&nxt[tm * 16 + c16][kt * 32 + quad * 8];
            *(short8*)&hs[(((btile + tm) * 20 + t * 4 + kt) << 9) + lane * 8] = v;
        }
    }
}

// ---------------------------------------------------------------------------
// mlp: fused 640->576(531)->256->64->2 + softmax. 32 samples/block, 256 thr.
// hs read as packed A-tiles; weights as packed B-tiles (all 16B/lane).
// ---------------------------------------------------------------------------
__global__ __launch_bounds__(256, 2) void mlp_kernel(
    const short* __restrict__ hs,
    const short* __restrict__ W1p, const float* __restrict__ b1p,
    const short* __restrict__ W2p, const float* __restrict__ b2,
    const short* __restrict__ W3p, const float* __restrict__ b3,
    const float* __restrict__ W4,  const float* __restrict__ b4,
    float* __restrict__ out)
{
    __shared__ __align__(16) short a1[32][584];
    __shared__ __align__(16) short a2[32][264];
    __shared__ __align__(16) short a3[32][72];
    const int tid  = threadIdx.x;
    const int w    = tid >> 6;
    const int lane = tid & 63;
    const int quad = lane >> 4;
    const int c16  = lane & 15;
    const int m0   = blockIdx.x * 32;
    const int mtile = blockIdx.x * 2;

    // ---- layer 1: K=640, N=576 (9 n-tiles per wave) ----
    {
        f32x4 acc[2][9];
#pragma unroll
        for (int mt = 0; mt < 2; ++mt)
#pragma unroll
            for (int i = 0; i < 9; ++i)
                acc[mt][i] = (f32x4){0.f, 0.f, 0.f, 0.f};
#pragma unroll 4
        for (int ks = 0; ks < 20; ++ks) {
            short8 a[2];
#pragma unroll
            for (int mt = 0; mt < 2; ++mt)
                a[mt] = *(const short8*)&hs[(((mtile + mt) * 20 + ks) << 9) + lane * 8];
#pragma unroll
            for (int i = 0; i < 9; ++i) {
                short8 b = *(const short8*)&W1p[(((w * 9 + i) * 20 + ks) << 9) + lane * 8];
                acc[0][i] = MFMA(a[0], b, acc[0][i]);
                acc[1][i] = MFMA(a[1], b, acc[1][i]);
            }
        }
#pragma unroll
        for (int i = 0; i < 9; ++i) {
            int n = (w * 9 + i) * 16 + c16;
            float bv = b1p[n];
#pragma unroll
            for (int mt = 0; mt < 2; ++mt)
#pragma unroll
                for (int r = 0; r < 4; ++r) {
                    int m = mt * 16 + quad * 4 + r;
                    float v = acc[mt][i][r] + bv;
                    a1[m][n] = f2bs(v > 0.f ? v : 0.f);
                }
        }
    }
    __syncthreads();

    // ---- layer 2: K=544, N=256 (4 n-tiles per wave) ----
    {
        f32x4 acc[2][4];
#pragma unroll
        for (int mt = 0; mt < 2; ++mt)
#pragma unroll
            for (int i = 0; i < 4; ++i)
                acc[mt][i] = (f32x4){0.f, 0.f, 0.f, 0.f};
#pragma unroll 4
        for (int ks = 0; ks < 17; ++ks) {
            short8 a[2];
#pragma unroll
            for (int mt = 0; mt < 2; ++mt)
                a[mt] = *(const short8*)&a1[mt * 16 + c16][ks * 32 + quad * 8];
#pragma unroll
            for (int i = 0; i < 4; ++i) {
                short8 b = *(const short8*)&W2p[(((w * 4 + i) * 17 + ks) << 9) + lane * 8];
                acc[0][i] = MFMA(a[0], b, acc[0][i]);
                acc[1][i] = MFMA(a[1], b, acc[1][i]);
            }
        }
#pragma unroll
        for (int i = 0; i < 4; ++i) {
            int n = (w * 4 + i) * 16 + c16;
            float bv = b2[n];
#pragma unroll
            for (int mt = 0; mt < 2; ++mt)
#pragma unroll
                for (int r = 0; r < 4; ++r) {
                    int m = mt * 16 + quad * 4 + r;
                    float v = acc[mt][i][r] + bv;
                    a2[m][n] = f2bs(v > 0.f ? v : 0.f);
                }
        }
    }
    __syncthreads();

    // ---- layer 3: K=256, N=64 (1 n-tile per wave) ----
    {
        f32x4 acc[2];
        acc[0] = (f32x4){0.f, 0.f, 0.f, 0.f};
        acc[1] = (f32x4){0.f, 0.f, 0.f, 0.f};
#pragma unroll
        for (int ks = 0; ks < 8; ++ks) {
            short8 a[2];
#pragma unroll
            for (int mt = 0; mt < 2; ++mt)
                a[mt] = *(const short8*)&a2[mt * 16 + c16][ks * 32 + quad * 8];
            short8 b = *(const short8*)&W3p[((w * 8 + ks) << 9) + lane * 8];
            acc[0] = MFMA(a[0], b, acc[0]);
            acc[1] = MFMA(a[1], b, acc[1]);
        }
        int n = w * 16 + c16;
        float bv = b3[n];
#pragma unroll
        for (int mt = 0; mt < 2; ++mt)
#pragma unroll
            for (int r = 0; r < 4; ++r) {
                int m = mt * 16 + quad * 4 + r;
                float v = acc[mt][r] + bv;
                a3[m][n] = f2bs(v > 0.f ? v : 0.f);
            }
    }
    __syncthreads();

    // ---- layer 4 + softmax on wave 0 ----
    if (tid < 64) {
        int m   = tid >> 1;
        int cls = tid & 1;
        float s = b4[cls];
#pragma unroll 8
        for (int k = 0; k < 64; ++k)
            s += b2f(a3[m][k]) * W4[cls * 64 + k];
        float other = __shfl_xor(s, 1);
        float p = 1.f / (1.f + __expf(other - s));
        out[(m0 + m) * 2 + cls] = p;
    }
}

// ---------------------------------------------------------------------------
extern "C" void kernel_launch(void* const* d_in, const int* in_sizes, int n_in,
                              void* d_out, int out_size, void* d_ws, size_t ws_size,
                              hipStream_t stream)
{
    (void)in_sizes; (void)n_in; (void)out_size;
    if (ws_size < (size_t)WS_NEED) return;

    const float* x1   = (const float*)d_in[0];
    const float* x2   = (const float*)d_in[1];
    const float* W_ih = (const float*)d_in[2];
    const float* W_hh = (const float*)d_in[3];
    const float* b_ih = (const float*)d_in[4];
    const float* b_hh = (const float*)d_in[5];
    const float* W1   = (const float*)d_in[6];
    const float* b1   = (const float*)d_in[7];
    const float* W2   = (const float*)d_in[8];
    const float* b2   = (const float*)d_in[9];
    const float* W3   = (const float*)d_in[10];
    const float* b3   = (const float*)d_in[11];
    const float* W4   = (const float*)d_in[12];
    const float* b4   = (const float*)d_in[13];

    char* ws = (char*)d_ws;
    short* Wihp  = (short*)(ws + O_WIH);
    short* Whhp  = (short*)(ws + O_WHH);
    short* W1p   = (short*)(ws + O_W1);
    short* W2p   = (short*)(ws + O_W2);
    short* W3p   = (short*)(ws + O_W3);
    float* biasg = (float*)(ws + O_BG);
    float* b1p   = (float*)(ws + O_B1);
    short* xg    = (short*)(ws + O_XG);
    short* hsb   = (short*)(ws + O_HS);

    prep_kernel<<<3461, 256, 0, stream>>>(W_ih, W_hh, b_ih, b_hh, W1, b1, W2, W3,
                                          Wihp, Whhp, biasg, W1p, b1p, W2p, W3p);
    k1_xgemm<<<1280, 512, 0, stream>>>(x1, x2, Wihp, biasg, xg);
    k2_rec<<<512, 512, 0, stream>>>(Whhp, xg, hsb);
    mlp_kernel<<<512, 256, 0, stream>>>(hsb, W1p, b1p, W2p, b2, W3p, b3, W4, b4,
                                        (float*)d_out);
}